// Round 3
// baseline (1259.170 us; speedup 1.0000x reference)
//
#include <hip/hip_runtime.h>
#include <stdint.h>

// Two-phase LoadingModel CAVI update: n=1000, p=50000, z=20, l=10.
//
// Phase A (3582x128, plain launch): bandwidth phase, partial-split for
//   occupancy (ztx over NSZ=4 n-slices, W over NSW=5 l-slices). Partials
//   stash into the OUT buffers; phase B sums them in its prologue.
//   Hazard analysis (unchanged, still valid): every cross-thread write into
//   the stash regions happens after the tag-1 global combine, which in turn
//   requires every block's prologue reads to have completed. The only
//   earlier write is step (0,0)'s out_mw[col] = same-thread read-then-write.
//
// Phase B (cooperative 53x1024): latency phase, 200 sequential global
//   softmaxes. NEW this round: ZERO __syncthreads in the step loop. The HIP
//   compiler drains vmcnt(0)/lgkmcnt(0) before every s_barrier, which put
//   every work wave's in-flight HBM stores + prefetch loads on the comm
//   critical path twice per step. Replaced with tagged LDS mailboxes:
//     work wave lane0 -> lds_m/lds_s[parity][wid]  (tag<<32 | f32 bits)
//     comm wave (wid 0) polls 15 tags, merges, publishes global slot,
//       polls 53 slots (1 load/lane), posts lds_res[parity] (tag|lse)
//     work waves spin on lds_res tag.
//   Tag-in-word messages are self-contained (relaxed atomics); parity
//   double-buffer + the grid-wide happens-before chain (a wave reaches step
//   s+2 only after every block consumed step s+1) makes overwrites safe.
//   Comm wave runs at s_setprio(1): it is the critical path.

#define NTA 128
#define NBA 398             // blocks per slice in phase A: 398*128 = 50944
#define NSZ 4               // n-slices for ztx (250 rows each)
#define NSW 5               // l-slices for W (2 l each)
#define PSTRIDE 50944       // padded column stride for stashes

#define NT_B 1024
#define NWAVE_B 16
#define COLS_B 960          // 15 work waves * 64
#define NBLK_B 53           // 53*960 = 50880 >= 50000

constexpr int N_DIM = 1000;
constexpr int P_DIM = 50000;
constexpr int Z_DIM = 20;
constexpr int L_DIM = 10;
constexpr int NSTEP = Z_DIM * L_DIM;   // 200

static_assert(NTA * NBA == PSTRIDE, "A covers PSTRIDE columns");
static_assert(NBLK_B * COLS_B >= P_DIM, "B covers all real columns");
static_assert(NBLK_B * COLS_B <= PSTRIDE, "B stash reads in bounds");
static_assert(NBLK_B <= 64, "one poll load per lane");

using u64 = unsigned long long;

__device__ __forceinline__ float wred_max(float v) {
#pragma unroll
  for (int m = 32; m; m >>= 1) v = fmaxf(v, __shfl_xor(v, m, 64));
  return v;
}
__device__ __forceinline__ float wred_sum(float v) {
#pragma unroll
  for (int m = 32; m; m >>= 1) v += __shfl_xor(v, m, 64);
  return v;
}
__device__ __forceinline__ u64 tagpack(int s, float v) {
  return (((u64)(unsigned)s) << 32) | (u64)__float_as_uint(v);
}

// ---------------- Phase A: bandwidth-bound precompute ----------------
__global__ __launch_bounds__(NTA) void precompute_kernel(
    const float* __restrict__ data,      // [n, p]
    const float* __restrict__ mean_z,    // [n, z]
    const float* __restrict__ mean_zz,   // [z, z]
    const float* __restrict__ mean_w_in, // [l, z, p]
    const float* __restrict__ alpha_in,  // [l, z, p]
    const float* __restrict__ tau_p,     // scalar
    const float* __restrict__ tau0,      // [l, z]
    float* __restrict__ ztx_stash,       // [NSZ][z][PSTRIDE] (= out_mw)
    float* __restrict__ W_stash,         // [NSW][z][PSTRIDE] (= out_alpha)
    float* __restrict__ out_vw)          // [l, z]
{
  const int bid  = blockIdx.x;
  const int role = bid / NBA;            // 0..NSZ-1: ztx; NSZ..NSZ+NSW-1: W
  const int b2   = bid % NBA;
  const int col  = b2 * NTA + threadIdx.x;   // < PSTRIDE by construction
  const bool act = (col < P_DIM);

  if (role == 0 && b2 < 2) {
    int g = b2 * NTA + threadIdx.x;
    if (g < L_DIM * Z_DIM) {
      int k = g % Z_DIM;
      out_vw[g] = 1.0f / (tau_p[0] * mean_zz[k * Z_DIM + k] + tau0[g]);
    }
  }

  if (role < NSZ) {
    // ztx partial over rows [s*250, s*250+250)
    const int s  = role;
    const int n0 = s * (N_DIM / NSZ);
    const int n1 = n0 + (N_DIM / NSZ);
    float z[Z_DIM];
#pragma unroll
    for (int k = 0; k < Z_DIM; k++) z[k] = 0.f;
    const float* dcol = data + col;
#pragma unroll 8
    for (int n = n0; n < n1; n++) {
      float d = act ? dcol[(size_t)n * P_DIM] : 0.f;
#pragma unroll
      for (int k = 0; k < Z_DIM; k++) z[k] += mean_z[n * Z_DIM + k] * d;
    }
#pragma unroll
    for (int k = 0; k < Z_DIM; k++)
      ztx_stash[(size_t)(s * Z_DIM + k) * PSTRIDE + col] = z[k];
  } else {
    // W partial over l in {2s, 2s+1}
    const int s = role - NSZ;
    float Wp[Z_DIM];
#pragma unroll
    for (int j = 0; j < Z_DIM; j++) Wp[j] = 0.f;
#pragma unroll
    for (int li = 0; li < 2; li++) {
      const int l = 2 * s + li;
#pragma unroll
      for (int j = 0; j < Z_DIM; j++) {
        if (act) {
          size_t idx = ((size_t)(l * Z_DIM + j)) * P_DIM + col;
          Wp[j] += mean_w_in[idx] * alpha_in[idx];
        }
      }
    }
#pragma unroll
    for (int j = 0; j < Z_DIM; j++)
      W_stash[(size_t)(s * Z_DIM + j) * PSTRIDE + col] = Wp[j];
  }
}

// ---------------- Phase B: latency-bound sequential loop ----------------
__global__ __launch_bounds__(NT_B) void loading_model_seq(
    const float* __restrict__ mean_zz,   // [z, z]
    const float* __restrict__ mean_w_in, // [l, z, p]
    const float* __restrict__ alpha_in,  // [l, z, p]
    const float* __restrict__ tau_p,     // scalar
    const float* __restrict__ tau0,      // [l, z]
    const float* __restrict__ pi,        // [z, p]
    const float* __restrict__ ztx_stash, // [NSZ][z][PSTRIDE]
    const float* __restrict__ W_stash,   // [NSW][z][PSTRIDE]
    float* __restrict__ out_mw,          // [l, z, p]
    float* __restrict__ out_alpha,       // [l, z, p]
    u64* __restrict__ slots)             // [2][NBLK_B]
{
  const int tid  = threadIdx.x;
  const int blk  = blockIdx.x;
  const int lane = tid & 63;
  const int wid  = tid >> 6;             // 0 = comm wave, 1..15 = work
  const float tau = tau_p[0];

  __shared__ u64 lds_m[2][NWAVE_B];      // (tag | wmax) per work wave
  __shared__ u64 lds_s[2][NWAVE_B];      // (tag | wsum) per work wave
  __shared__ u64 lds_res[2];             // (tag | global lse)

  if (tid < NWAVE_B) {
    lds_m[0][tid] = 0; lds_m[1][tid] = 0;
    lds_s[0][tid] = 0; lds_s[1][tid] = 0;
  }
  if (tid == 0) { lds_res[0] = 0; lds_res[1] = 0; }
  __syncthreads();   // one-time: LDS init visible; no barriers after this

  // ================= comm wave =================
  if (wid == 0) {
    __builtin_amdgcn_s_setprio(1);       // critical-path wave
    for (int s = 1; s <= NSTEP; s++) {
      const int buf = s & 1;
      const bool val = (lane >= 1 && lane < NWAVE_B);
      u64 rm = 0, rs = 0;
      bool nm = val, ns = val;
      while (nm || ns) {
        if (nm) {
          rm = __hip_atomic_load(&lds_m[buf][lane], __ATOMIC_RELAXED,
                                 __HIP_MEMORY_SCOPE_WORKGROUP);
          if ((unsigned)(rm >> 32) == (unsigned)s) nm = false;
        }
        if (ns) {
          rs = __hip_atomic_load(&lds_s[buf][lane], __ATOMIC_RELAXED,
                                 __HIP_MEMORY_SCOPE_WORKGROUP);
          if ((unsigned)(rs >> 32) == (unsigned)s) ns = false;
        }
      }
      float m  = val ? __uint_as_float((unsigned)rm) : -INFINITY;
      float sv = val ? __uint_as_float((unsigned)rs) : 0.f;
      float M  = wred_max(m);
      float S  = wred_sum(val ? __expf(m - M) * sv : 0.f);
      if (lane == 0) {
        float lse_b = M + __logf(S);
        __hip_atomic_store(&slots[buf * NBLK_B + blk], tagpack(s, lse_b),
                           __ATOMIC_RELAXED, __HIP_MEMORY_SCOPE_AGENT);
      }
      bool need = (lane < NBLK_B);
      u64 raw = 0;
      while (need) {
        raw = __hip_atomic_load(&slots[buf * NBLK_B + lane], __ATOMIC_RELAXED,
                                __HIP_MEMORY_SCOPE_AGENT);
        if ((unsigned)(raw >> 32) == (unsigned)s) need = false;
      }
      float bl = (lane < NBLK_B) ? __uint_as_float((unsigned)raw) : -INFINITY;
      float Mg = wred_max(bl);
      float Sg = wred_sum((lane < NBLK_B) ? __expf(bl - Mg) : 0.f);
      if (lane == 0)
        __hip_atomic_store(&lds_res[buf], tagpack(s, Mg + __logf(Sg)),
                           __ATOMIC_RELAXED, __HIP_MEMORY_SCOPE_WORKGROUP);
    }
    return;
  }

  // ================= work waves =================
  const int col = blk * COLS_B + (tid - 64);
  const bool active = (col < P_DIM);

  // prologue: sum stash partials (all blocks' prologue reads complete
  // before any block's tag-1-gated writes; see header)
  float ztx[Z_DIM], W[Z_DIM];
#pragma unroll
  for (int k = 0; k < Z_DIM; k++) ztx[k] = 0.f;
#pragma unroll
  for (int j = 0; j < Z_DIM; j++) W[j] = 0.f;
#pragma unroll
  for (int s = 0; s < NSZ; s++)
#pragma unroll
    for (int k = 0; k < Z_DIM; k++)
      ztx[k] += ztx_stash[(size_t)(s * Z_DIM + k) * PSTRIDE + col];
#pragma unroll
  for (int s = 0; s < NSW; s++)
#pragma unroll
    for (int j = 0; j < Z_DIM; j++)
      W[j] += W_stash[(size_t)(s * Z_DIM + j) * PSTRIDE + col];

  float pival = active ? pi[col] : 1.0f;
  float lpk   = active ? __logf(pival) : -INFINITY;   // k=0
  float nlpk  = lpk;
  float mw = 0.f, av = 0.f;
  if (active) { mw = mean_w_in[col]; av = alpha_in[col]; } // (l=0,k=0)

  // Step-constant prefetch (kept off the critical path thereafter).
  const float E0    = mean_zz[0];
  const float ktau0 = tau * E0;
  float cs2   = 1.0f / ktau0;
  float czsc2 = tau / E0;
  float nc0, nc1, nmnc;
  {
    const float t0    = tau0[0];
    const float s0inv = 1.0f / t0;
    const float s2p   = cs2 + s0inv;
    nc0  = 0.5f * (__logf(cs2) - __logf(s2p));
    nc1  = 0.5f * czsc2 * (s0inv / s2p);
    nmnc = tau / (ktau0 + t0);
  }

#pragma unroll
  for (int k = 0; k < Z_DIM; k++) {
    const float E    = mean_zz[k * Z_DIM + k];
    const float ktau = tau * E;

    float acc = 0.f;
#pragma unroll
    for (int j = 0; j < Z_DIM; j++) acc += mean_zz[k * Z_DIM + j] * W[j];
    const float RtZk = ztx[k] - (acc - E * W[k]);
    if (k + 1 < Z_DIM && active) pival = pi[(size_t)(k + 1) * P_DIM + col];

    float Wk = W[k];
    for (int l = 0; l < L_DIM; l++) {
      const float c0  = nc0;
      const float c1  = nc1;
      const float mnc = nmnc;

      const float Wkl = Wk - mw * av;
      const float E_R = RtZk - E * Wkl;
      const float mean_new = mnc * E_R;
      float logit = lpk + c0 + c1 * E_R * E_R;
      if (!active) logit = -INFINITY;

      const size_t oidx = ((size_t)(l * Z_DIM + k)) * P_DIM + col;
      if (active) out_mw[oidx] = mean_new;   // fire-and-forget

      // ---- per-wave softmax stats -> tagged LDS mailbox ----
      float wmax = wred_max(logit);
      float ew   = active ? __expf(logit - wmax) : 0.f;
      float wsum = wred_sum(ew);
      const int s   = k * L_DIM + l + 1;   // step tag, 1..200
      const int buf = s & 1;
      if (lane == 0) {
        __hip_atomic_store(&lds_m[buf][wid], tagpack(s, wmax),
                           __ATOMIC_RELAXED, __HIP_MEMORY_SCOPE_WORKGROUP);
        __hip_atomic_store(&lds_s[buf][wid], tagpack(s, wsum),
                           __ATOMIC_RELAXED, __HIP_MEMORY_SCOPE_WORKGROUP);
      }

      // ---- overlap with the wait: next step's mean_w/alpha + constants ----
      float mw_n = 0.f, av_n = 0.f;
      {
        int ln = l + 1, kn = k;
        if (ln == L_DIM) { ln = 0; kn = k + 1; }
        if (kn < Z_DIM) {
          if (active) {
            size_t idx2 = ((size_t)(ln * Z_DIM + kn)) * P_DIM + col;
            mw_n = mean_w_in[idx2];
            av_n = alpha_in[idx2];
          }
          if (ln == 0) {  // entering next k: refresh per-k constants
            const float En = mean_zz[kn * Z_DIM + kn];
            const float kt = tau * En;
            cs2   = 1.0f / kt;
            czsc2 = tau / En;
            nlpk  = active ? __logf(pival) : -INFINITY;
          }
          const float t0n   = tau0[ln * Z_DIM + kn];
          const float s0inv = 1.0f / t0n;
          const float s2p   = cs2 + s0inv;
          nc0  = 0.5f * (__logf(cs2) - __logf(s2p));
          nc1  = 0.5f * czsc2 * (s0inv / s2p);
          nmnc = (ln == 0) ? tau / (tau * mean_zz[kn * Z_DIM + kn] + t0n)
                           : tau / (ktau + t0n);
        }
      }

      // ---- wait for the global lse (tagged LDS word) ----
      u64 r;
      do {
        r = __hip_atomic_load(&lds_res[buf], __ATOMIC_RELAXED,
                              __HIP_MEMORY_SCOPE_WORKGROUP);
      } while ((unsigned)(r >> 32) != (unsigned)s);
      const float LSEt = __uint_as_float((unsigned)r);

      const float alpha_new = active ? __expf(logit - LSEt) : 0.f;
      Wk = Wkl + mean_new * alpha_new;
      if (active) out_alpha[oidx] = alpha_new;
      mw = mw_n;
      av = av_n;
    }
    W[k] = Wk;  // commit for subsequent factors' RtZk
    lpk  = nlpk;
  }
}

extern "C" void kernel_launch(void* const* d_in, const int* in_sizes, int n_in,
                              void* d_out, int out_size, void* d_ws, size_t ws_size,
                              hipStream_t stream) {
  const float* data    = (const float*)d_in[0];
  const float* mean_z  = (const float*)d_in[1];
  const float* mean_zz = (const float*)d_in[2];
  const float* mean_w  = (const float*)d_in[3];
  // d_in[4] = var_w (unused: fully overwritten)
  const float* alpha   = (const float*)d_in[5];
  const float* tau     = (const float*)d_in[6];
  const float* tau0    = (const float*)d_in[7];
  const float* pi      = (const float*)d_in[8];

  float* out_mw    = (float*)d_out;
  float* out_vw    = out_mw + (size_t)L_DIM * Z_DIM * P_DIM;
  float* out_alpha = out_vw + (size_t)L_DIM * Z_DIM;
  u64*   ws        = (u64*)d_ws;

  // Stashes live in the out buffers (16.3 MB and 20.4 MB, both < 40 MB;
  // fully overwritten later).
  float* ztx_stash = out_mw;
  float* W_stash   = out_alpha;

  hipMemsetAsync(d_ws, 0, 2 * NBLK_B * sizeof(u64), stream);

  hipLaunchKernelGGL(precompute_kernel, dim3((NSZ + NSW) * NBA), dim3(NTA),
                     0, stream,
                     data, mean_z, mean_zz, mean_w, alpha, tau, tau0,
                     ztx_stash, W_stash, out_vw);

  void* args[] = {(void*)&mean_zz, (void*)&mean_w, (void*)&alpha,
                  (void*)&tau, (void*)&tau0, (void*)&pi,
                  (void*)&ztx_stash, (void*)&W_stash,
                  (void*)&out_mw, (void*)&out_alpha, (void*)&ws};
  hipLaunchCooperativeKernel((void*)loading_model_seq, dim3(NBLK_B),
                             dim3(NT_B), args, 0, stream);
}

// Round 4
// 1152.469 us; speedup vs baseline: 1.0926x; 1.0926x over previous
//
#include <hip/hip_runtime.h>
#include <stdint.h>

// Two-phase LoadingModel CAVI update: n=1000, p=50000, z=20, l=10.
//
// Phase A (3582x128, plain launch): bandwidth phase, partial-split for
//   occupancy (ztx over NSZ=4 n-slices, W over NSW=5 l-slices). Both partial
//   stashes now live in OUT_ALPHA (W stash at [0], ztx partials after it,
//   9.17M of 10M floats). All stash data is PROLOGUE-READ in phase B, which
//   is safe: the first cross-thread write into out_alpha happens after the
//   tag-1 global combine, which requires every block's prologue to be done.
//
// Phase B (cooperative 25x1024, CPT=2 columns/thread): latency phase, 200
//   sequential global softmaxes. ROUND 2/3 POST-MORTEM: dedicated comm wave
//   (4.0us/step) and barrier-free mailboxes (4.4us/step) both regressed vs
//   round 1's structure (3.4us/step: all waves work, 2 barriers, wave0
//   merges+publishes+polls). Binding constraint is publish-visibility +
//   poll scope + stragglers, all of which scale with BLOCK COUNT
//   (196->49 blocks: 5.3->3.4us/step). So: revert to round-1 structure and
//   halve the communicator: 25 blocks, 25 slots (4 cache lines), CPT=2.
//
//   VGPR fit (1024-thr block needs <=128): ztx[20]/col is NOT carried.
//   Prologue sums the 4 ztx partials into a summed-ztx ZONE at out_mw
//   planes 160..179 (stride P_DIM, zone plane k == out_mw plane 160+k);
//   each factor's ztx is reloaded (1 load/col) in the k-boundary overlap
//   window. Hazard proof: the only out_mw plane overlapping zone plane
//   160+k is itself = output (l=8,k''=k), written at step 10k+9; the zone
//   read is at step 10k (9 steps earlier, same thread, reg-dependence-
//   ordered). __restrict__ dropped on aliasing pointers.

#define NTA 128
#define NBA 398             // blocks per slice in phase A: 398*128 = 50944
#define NSZ 4               // n-slices for ztx (250 rows each)
#define NSW 5               // l-slices for W (2 l each)
#define PSTRIDE 50944       // padded column stride for stashes

#define NT_B 1024
#define NWAVE_B 16
#define CPT 2               // columns per thread
#define COLS_B (NT_B * CPT) // 2048
#define NBLK_B 25           // 25*2048 = 51200 >= 50000

constexpr int N_DIM = 1000;
constexpr int P_DIM = 50000;
constexpr int Z_DIM = 20;
constexpr int L_DIM = 10;
constexpr int ZONE_P0 = 160;   // summed-ztx zone: out_mw planes 160..179

static_assert(NTA * NBA == PSTRIDE, "A covers PSTRIDE columns");
static_assert(NBLK_B * COLS_B >= P_DIM, "B covers all real columns");
static_assert(NBLK_B <= 64, "one poll load per lane");

using u64 = unsigned long long;

__device__ __forceinline__ float wred_max(float v) {
#pragma unroll
  for (int m = 32; m; m >>= 1) v = fmaxf(v, __shfl_xor(v, m, 64));
  return v;
}
__device__ __forceinline__ float wred_sum(float v) {
#pragma unroll
  for (int m = 32; m; m >>= 1) v += __shfl_xor(v, m, 64);
  return v;
}
__device__ __forceinline__ u64 tagpack(int s, float v) {
  return (((u64)(unsigned)s) << 32) | (u64)__float_as_uint(v);
}

// ---------------- Phase A: bandwidth-bound precompute ----------------
__global__ __launch_bounds__(NTA) void precompute_kernel(
    const float* __restrict__ data,      // [n, p]
    const float* __restrict__ mean_z,    // [n, z]
    const float* __restrict__ mean_zz,   // [z, z]
    const float* __restrict__ mean_w_in, // [l, z, p]
    const float* __restrict__ alpha_in,  // [l, z, p]
    const float* __restrict__ tau_p,     // scalar
    const float* __restrict__ tau0,      // [l, z]
    float* __restrict__ ztx_part,        // [NSZ][z][PSTRIDE] (in out_alpha)
    float* __restrict__ W_stash,         // [NSW][z][PSTRIDE] (in out_alpha)
    float* __restrict__ out_vw)          // [l, z]
{
  const int bid  = blockIdx.x;
  const int role = bid / NBA;            // 0..NSZ-1: ztx; NSZ..NSZ+NSW-1: W
  const int b2   = bid % NBA;
  const int col  = b2 * NTA + threadIdx.x;   // < PSTRIDE by construction
  const bool act = (col < P_DIM);

  if (role == 0 && b2 < 2) {
    int g = b2 * NTA + threadIdx.x;
    if (g < L_DIM * Z_DIM) {
      int k = g % Z_DIM;
      out_vw[g] = 1.0f / (tau_p[0] * mean_zz[k * Z_DIM + k] + tau0[g]);
    }
  }

  if (role < NSZ) {
    const int s  = role;
    const int n0 = s * (N_DIM / NSZ);
    const int n1 = n0 + (N_DIM / NSZ);
    float z[Z_DIM];
#pragma unroll
    for (int k = 0; k < Z_DIM; k++) z[k] = 0.f;
    const float* dcol = data + col;
#pragma unroll 8
    for (int n = n0; n < n1; n++) {
      float d = act ? dcol[(size_t)n * P_DIM] : 0.f;
#pragma unroll
      for (int k = 0; k < Z_DIM; k++) z[k] += mean_z[n * Z_DIM + k] * d;
    }
#pragma unroll
    for (int k = 0; k < Z_DIM; k++)
      ztx_part[(size_t)(s * Z_DIM + k) * PSTRIDE + col] = z[k];
  } else {
    const int s = role - NSZ;
    float Wp[Z_DIM];
#pragma unroll
    for (int j = 0; j < Z_DIM; j++) Wp[j] = 0.f;
#pragma unroll
    for (int li = 0; li < 2; li++) {
      const int l = 2 * s + li;
#pragma unroll
      for (int j = 0; j < Z_DIM; j++) {
        if (act) {
          size_t idx = ((size_t)(l * Z_DIM + j)) * P_DIM + col;
          Wp[j] += mean_w_in[idx] * alpha_in[idx];
        }
      }
    }
#pragma unroll
    for (int j = 0; j < Z_DIM; j++)
      W_stash[(size_t)(s * Z_DIM + j) * PSTRIDE + col] = Wp[j];
  }
}

// ---------------- Phase B: latency-bound sequential loop ----------------
__global__ __launch_bounds__(NT_B) void loading_model_seq(
    const float* __restrict__ mean_zz,   // [z, z]
    const float* __restrict__ mean_w_in, // [l, z, p]
    const float* __restrict__ alpha_in,  // [l, z, p]
    const float* __restrict__ tau_p,     // scalar
    const float* __restrict__ tau0,      // [l, z]
    const float* __restrict__ pi,        // [z, p]
    const float* ztx_part,               // [NSZ][z][PSTRIDE] (aliases out_alpha)
    const float* W_stash,                // [NSW][z][PSTRIDE] (aliases out_alpha)
    float* zone,                         // [z][P_DIM] = out_mw + 160*P_DIM
    float* out_mw,                       // [l, z, p]
    float* out_alpha,                    // [l, z, p]
    u64* __restrict__ slots)             // [2][NBLK_B]
{
  const int tid  = threadIdx.x;
  const int blk  = blockIdx.x;
  const int lane = tid & 63;
  const int wid  = tid >> 6;
  const float tau = tau_p[0];

  int col[CPT]; bool act[CPT]; int colc[CPT];
#pragma unroll
  for (int c = 0; c < CPT; c++) {
    col[c]  = blk * COLS_B + c * NT_B + tid;
    act[c]  = (col[c] < P_DIM);
    colc[c] = act[c] ? col[c] : (P_DIM - 1);   // clamped for loads only
  }

  __shared__ float lds_wmax[NWAVE_B];
  __shared__ float lds_wsum[NWAVE_B];
  __shared__ float lds_lse;

  // ---- prologue: W carried; ztx summed into the zone (k=0 carried) ----
  float W[CPT][Z_DIM];
#pragma unroll
  for (int c = 0; c < CPT; c++)
#pragma unroll
    for (int j = 0; j < Z_DIM; j++) {
      float w = 0.f;
#pragma unroll
      for (int s = 0; s < NSW; s++)
        w += W_stash[(size_t)(s * Z_DIM + j) * PSTRIDE + colc[c]];
      W[c][j] = w;
    }

  float ztxc[CPT];
#pragma unroll
  for (int k = 0; k < Z_DIM; k++) {
#pragma unroll
    for (int c = 0; c < CPT; c++) {
      float z = 0.f;
#pragma unroll
      for (int s = 0; s < NSZ; s++)
        z += ztx_part[(size_t)(s * Z_DIM + k) * PSTRIDE + colc[c]];
      if (k == 0) ztxc[c] = z;
      else if (act[c]) zone[(size_t)k * P_DIM + col[c]] = z;
    }
  }

  float pival[CPT], lpk[CPT], nlpk[CPT];
  float mw[CPT], av[CPT];
#pragma unroll
  for (int c = 0; c < CPT; c++) {
    pival[c] = pi[colc[c]];
    lpk[c]   = act[c] ? __logf(pival[c]) : -INFINITY;
    nlpk[c]  = lpk[c];
    mw[c] = mean_w_in[colc[c]];
    av[c] = alpha_in[colc[c]];
  }

  // Step-constant prefetch (kept off the critical path thereafter).
  const float E0    = mean_zz[0];
  const float ktau0 = tau * E0;
  float cs2   = 1.0f / ktau0;
  float czsc2 = tau / E0;
  float nc0, nc1, nmnc;
  {
    const float t0    = tau0[0];
    const float s0inv = 1.0f / t0;
    const float s2p   = cs2 + s0inv;
    nc0  = 0.5f * (__logf(cs2) - __logf(s2p));
    nc1  = 0.5f * czsc2 * (s0inv / s2p);
    nmnc = tau / (ktau0 + t0);
  }

  float ztxn[CPT] = {0.f, 0.f};

#pragma unroll
  for (int k = 0; k < Z_DIM; k++) {
    const float E    = mean_zz[k * Z_DIM + k];
    const float ktau = tau * E;

    float RtZk[CPT];
#pragma unroll
    for (int c = 0; c < CPT; c++) {
      float acc = 0.f;
#pragma unroll
      for (int j = 0; j < Z_DIM; j++) acc += mean_zz[k * Z_DIM + j] * W[c][j];
      RtZk[c] = ztxc[c] - (acc - E * W[c][k]);
    }
    if (k + 1 < Z_DIM) {
#pragma unroll
      for (int c = 0; c < CPT; c++)
        pival[c] = pi[(size_t)(k + 1) * P_DIM + colc[c]];
    }

    float Wk[CPT];
#pragma unroll
    for (int c = 0; c < CPT; c++) Wk[c] = W[c][k];

    for (int l = 0; l < L_DIM; l++) {
      const float c0  = nc0;
      const float c1  = nc1;
      const float mnc = nmnc;

      float Wkl[CPT], mean_new[CPT], logit[CPT];
#pragma unroll
      for (int c = 0; c < CPT; c++) {
        Wkl[c] = Wk[c] - mw[c] * av[c];
        const float E_R = RtZk[c] - E * Wkl[c];
        mean_new[c] = mnc * E_R;
        logit[c] = act[c] ? (lpk[c] + c0 + c1 * E_R * E_R) : -INFINITY;
        if (act[c])
          out_mw[((size_t)(l * Z_DIM + k)) * P_DIM + col[c]] = mean_new[c];
      }

      // ---- per-wave softmax stats over both columns ----
      float lmax = fmaxf(logit[0], logit[1]);
      float wmax = wred_max(lmax);
      float ew = 0.f;
#pragma unroll
      for (int c = 0; c < CPT; c++)
        if (act[c]) ew += __expf(logit[c] - wmax);
      float wsum = wred_sum(ew);
      if (lane == 0) { lds_wmax[wid] = wmax; lds_wsum[wid] = wsum; }
      __syncthreads();

      const int s   = k * L_DIM + l + 1;   // step tag, 1..200
      const int buf = s & 1;
      if (wid == 0) {
        // parallel 16-wave merge in wave 0; publish EARLY
        const bool val = (lane < NWAVE_B);
        float m  = val ? lds_wmax[lane] : -INFINITY;
        float sv = val ? lds_wsum[lane] : 0.f;
        float M  = wred_max(m);
        float S  = wred_sum(val ? __expf(m - M) * sv : 0.f);
        if (lane == 0)
          __hip_atomic_store(&slots[buf * NBLK_B + blk],
                             tagpack(s, M + __logf(S)),
                             __ATOMIC_RELAXED, __HIP_MEMORY_SCOPE_AGENT);
      }

      // ---- overlap with the wait: next step's prefetch + constants ----
      float mwn[CPT] = {0.f, 0.f}, avn[CPT] = {0.f, 0.f};
      {
        int ln = l + 1, kn = k;
        if (ln == L_DIM) { ln = 0; kn = k + 1; }
        if (kn < Z_DIM) {
#pragma unroll
          for (int c = 0; c < CPT; c++) {
            size_t idx2 = ((size_t)(ln * Z_DIM + kn)) * P_DIM + colc[c];
            mwn[c] = mean_w_in[idx2];
            avn[c] = alpha_in[idx2];
          }
          if (ln == 0) {  // entering next k: ztx from zone + per-k constants
            const float En = mean_zz[kn * Z_DIM + kn];
            cs2   = 1.0f / (tau * En);
            czsc2 = tau / En;
#pragma unroll
            for (int c = 0; c < CPT; c++) {
              ztxn[c] = zone[(size_t)kn * P_DIM + colc[c]];
              nlpk[c] = act[c] ? __logf(pival[c]) : -INFINITY;
            }
          }
          const float t0n   = tau0[ln * Z_DIM + kn];
          const float s0inv = 1.0f / t0n;
          const float s2p   = cs2 + s0inv;
          nc0  = 0.5f * (__logf(cs2) - __logf(s2p));
          nc1  = 0.5f * czsc2 * (s0inv / s2p);
          nmnc = (ln == 0) ? tau / (tau * mean_zz[kn * Z_DIM + kn] + t0n)
                           : tau / (ktau + t0n);
        }
      }

      // ---- flat one-hop combine: wave 0 polls 25 slots (1 load/lane) ----
      if (wid == 0) {
        bool need = (lane < NBLK_B);
        u64 raw = 0;
        while (need) {
          raw = __hip_atomic_load(&slots[buf * NBLK_B + lane], __ATOMIC_RELAXED,
                                  __HIP_MEMORY_SCOPE_AGENT);
          if ((unsigned)(raw >> 32) == (unsigned)s) need = false;
        }
        float bl = (lane < NBLK_B) ? __uint_as_float((unsigned)raw) : -INFINITY;
        float Mg = wred_max(bl);
        float Sg = wred_sum((lane < NBLK_B) ? __expf(bl - Mg) : 0.f);
        if (lane == 0) lds_lse = Mg + __logf(Sg);
      }
      __syncthreads();

      const float LSEt = lds_lse;
#pragma unroll
      for (int c = 0; c < CPT; c++) {
        const float alpha_new = act[c] ? __expf(logit[c] - LSEt) : 0.f;
        Wk[c] = Wkl[c] + mean_new[c] * alpha_new;
        if (act[c])
          out_alpha[((size_t)(l * Z_DIM + k)) * P_DIM + col[c]] = alpha_new;
        mw[c] = mwn[c];
        av[c] = avn[c];
      }
    }
#pragma unroll
    for (int c = 0; c < CPT; c++) {
      W[c][k] = Wk[c];   // commit for subsequent factors' RtZk
      ztxc[c] = ztxn[c];
      lpk[c]  = nlpk[c];
    }
  }
}

extern "C" void kernel_launch(void* const* d_in, const int* in_sizes, int n_in,
                              void* d_out, int out_size, void* d_ws, size_t ws_size,
                              hipStream_t stream) {
  const float* data    = (const float*)d_in[0];
  const float* mean_z  = (const float*)d_in[1];
  const float* mean_zz = (const float*)d_in[2];
  const float* mean_w  = (const float*)d_in[3];
  // d_in[4] = var_w (unused: fully overwritten)
  const float* alpha   = (const float*)d_in[5];
  const float* tau     = (const float*)d_in[6];
  const float* tau0    = (const float*)d_in[7];
  const float* pi      = (const float*)d_in[8];

  float* out_mw    = (float*)d_out;
  float* out_vw    = out_mw + (size_t)L_DIM * Z_DIM * P_DIM;
  float* out_alpha = out_vw + (size_t)L_DIM * Z_DIM;
  u64*   ws        = (u64*)d_ws;

  // Stashes in out_alpha: W stash 5.09M floats, ztx partials 4.08M floats
  // (9.17M of 10M). Summed-ztx zone: out_mw planes 160..179.
  float* W_stash   = out_alpha;
  float* ztx_part  = out_alpha + (size_t)NSW * Z_DIM * PSTRIDE;
  float* zone      = out_mw + (size_t)ZONE_P0 * P_DIM;

  hipMemsetAsync(d_ws, 0, 2 * NBLK_B * sizeof(u64), stream);

  hipLaunchKernelGGL(precompute_kernel, dim3((NSZ + NSW) * NBA), dim3(NTA),
                     0, stream,
                     data, mean_z, mean_zz, mean_w, alpha, tau, tau0,
                     ztx_part, W_stash, out_vw);

  void* args[] = {(void*)&mean_zz, (void*)&mean_w, (void*)&alpha,
                  (void*)&tau, (void*)&tau0, (void*)&pi,
                  (void*)&ztx_part, (void*)&W_stash, (void*)&zone,
                  (void*)&out_mw, (void*)&out_alpha, (void*)&ws};
  hipLaunchCooperativeKernel((void*)loading_model_seq, dim3(NBLK_B),
                             dim3(NT_B), args, 0, stream);
}